// Round 8
// baseline (3678.257 us; speedup 1.0000x reference)
//
#include <hip/hip_runtime.h>
#include <hip/hip_bf16.h>
#include <stdint.h>

#define B_ 256
#define T_ 150
#define S_ 151
#define E_ 512
#define H_ 8
#define L_ 6
#define FF_ 2048
#define M_ (B_*S_)   // 38656 = 302*128 = 151*256

typedef __hip_bfloat16 bf16;
typedef __bf16 bf16x8 __attribute__((ext_vector_type(8)));
typedef float f32x4 __attribute__((ext_vector_type(4)));
typedef unsigned short u16x8 __attribute__((ext_vector_type(8)));

__device__ inline unsigned short f2b(float x) {
    union { __hip_bfloat16 h; unsigned short u; } c;
    c.h = __float2bfloat16(x);
    return c.u;
}
__device__ inline float b2f(unsigned short u) {
    union { uint32_t u; float f; } c;
    c.u = (uint32_t)u << 16;
    return c.f;
}

// async global->LDS 16B; LDS dest must be wave-uniform base + lane*16 (linear)
__device__ __forceinline__ void gl16(const void* g, void* l) {
    __builtin_amdgcn_global_load_lds(
        (const __attribute__((address_space(1))) unsigned int*)g,
        (__attribute__((address_space(3))) unsigned int*)l, 16, 0, 0);
}

// ---------------- weight transpose f32[K][N] -> bf16[N][K], batched over L ----
__global__ __launch_bounds__(256)
void transpose_cast_kernel(const float* __restrict__ src, bf16* __restrict__ dst,
                           int K, int N) {
    __shared__ float tile[64][65];
    int l = blockIdx.z;
    const float* s = src + (size_t)l * K * N;
    bf16* d = dst + (size_t)l * K * N;
    int bk = blockIdx.x * 64, bn = blockIdx.y * 64;
    int col = threadIdx.x & 63, rg = threadIdx.x >> 6;
#pragma unroll
    for (int i = 0; i < 16; ++i) {
        int r = i * 4 + rg;
        tile[r][col] = s[(size_t)(bk + r) * N + bn + col];
    }
    __syncthreads();
#pragma unroll
    for (int i = 0; i < 16; ++i) {
        int r = i * 4 + rg;
        d[(size_t)(bn + r) * K + bk + col] = __float2bfloat16(tile[col][r]);
    }
}

// ---------------- token embedding + pos + cls -> xbf (4 rows/block) ----------
__global__ __launch_bounds__(256)
void embed_kernel(const int* __restrict__ tt, const int* __restrict__ dec_idx,
                  const float* __restrict__ action_val, const float* __restrict__ dis_val,
                  const float* __restrict__ v_val,
                  const float* __restrict__ action_W, const float* __restrict__ action_b,
                  const float* __restrict__ dis_W, const float* __restrict__ dis_b,
                  const float* __restrict__ v_W, const float* __restrict__ v_b,
                  const float* __restrict__ dec_emb, const float* __restrict__ pos,
                  const float* __restrict__ cls,
                  bf16* __restrict__ xbf) {
    int lane = threadIdx.x & 63;
    int bs = blockIdx.x * 4 + (threadIdx.x >> 6);
    int b = bs / S_, s = bs - b * S_;
    int e0 = lane * 8;
    f32x4 v0, v1;
    if (s == 0) {
        v0 = *(const f32x4*)(cls + e0);
        v1 = *(const f32x4*)(cls + e0 + 4);
    } else {
        int t = s - 1;
        int ty = tt[b * T_ + t];
        if (ty == 0) {
            float av = action_val[b * T_ + t];
            f32x4 w0 = *(const f32x4*)(action_W + e0);
            f32x4 w1 = *(const f32x4*)(action_W + e0 + 4);
            f32x4 b0 = *(const f32x4*)(action_b + e0);
            f32x4 b1 = *(const f32x4*)(action_b + e0 + 4);
            v0 = w0 * av + b0;  v1 = w1 * av + b1;
        } else if (ty == 1) {
            v0 = *(const f32x4*)(dis_b + e0) + *(const f32x4*)(v_b + e0);
            v1 = *(const f32x4*)(dis_b + e0 + 4) + *(const f32x4*)(v_b + e0 + 4);
#pragma unroll
            for (int i = 0; i < 10; ++i) {
                float dv = dis_val[(b * T_ + t) * 10 + i];
                v0 += *(const f32x4*)(dis_W + i * E_ + e0) * dv;
                v1 += *(const f32x4*)(dis_W + i * E_ + e0 + 4) * dv;
            }
#pragma unroll
            for (int i = 0; i < 3; ++i) {
                float vv = v_val[(b * T_ + t) * 3 + i];
                v0 += *(const f32x4*)(v_W + i * E_ + e0) * vv;
                v1 += *(const f32x4*)(v_W + i * E_ + e0 + 4) * vv;
            }
        } else {
            const float* de = dec_emb + (size_t)dec_idx[b * T_ + t] * E_;
            v0 = *(const f32x4*)(de + e0);
            v1 = *(const f32x4*)(de + e0 + 4);
        }
        v0 += *(const f32x4*)(pos + (size_t)t * E_ + e0);
        v1 += *(const f32x4*)(pos + (size_t)t * E_ + e0 + 4);
    }
    size_t o = (size_t)bs * E_ + e0;
    union { unsigned short s[8]; uint4 v; } pk;
    pk.s[0] = f2b(v0[0]); pk.s[1] = f2b(v0[1]); pk.s[2] = f2b(v0[2]); pk.s[3] = f2b(v0[3]);
    pk.s[4] = f2b(v1[0]); pk.s[5] = f2b(v1[1]); pk.s[6] = f2b(v1[2]); pk.s[7] = f2b(v1[3]);
    *(uint4*)((unsigned short*)xbf + o) = pk.v;
}

// ---------------- 256x128 bf16 MFMA GEMM, double-buffered counted-vmcnt ------
// C = A[Mrows,K] * Bt[N,K]^T (+bias[,relu]). BM=256, BN=128, BK=64.
// 512 threads = 8 waves (2M x 4N); per-wave 128x32 = 8x2 frags; acc = 64 VGPR
// (NF=2 keeps total regs ~150 — R6's NF=4 spilled at the 128-VGPR cap).
// Staging: global_load_lds w=16, linear LDS dest + inverse-swizzled source;
// 6 gl16/K-tile (4 A + 2 B). Pipeline (R6-proven-correct schedule):
//   STAGE(next buf); vmcnt(6) [= prev tile's loads done, next stays in
//   flight]; s_barrier; COMPUTE(cur); s_barrier.  Never vmcnt(0) in-loop.
// Last m-tile may be partial: C-writes row-clamped; A staging over-reads land
// in the successor workspace buffer (allocation order guarantees owned mem).
// MODE: 1 = relu(acc+bias) | 3 = acc+bias
template<int MODE>
__global__ __launch_bounds__(512)
void gemm256_kernel(const bf16* __restrict__ A, const bf16* __restrict__ Bt,
                    const float* __restrict__ bias, bf16* __restrict__ Cb,
                    int Mrows, int N, int K) {
    extern __shared__ char smem[];
    char* const As0 = smem;                 // 32 KB
    char* const As1 = smem + 32768;         // 32 KB
    char* const Bs0 = smem + 65536;         // 16 KB
    char* const Bs1 = smem + 81920;         // 16 KB

    const int tid = threadIdx.x;
    const int w = tid >> 6, lane = tid & 63;
    const int l15 = lane & 15, lg = lane >> 4;
    const int wr = w >> 2, wc = w & 3;

    const int nwg = gridDim.x, bid = blockIdx.x;
    const int Ntl = N >> 7;
    const int q = nwg >> 3, r = nwg & 7;
    const int xcd = bid & 7, slot = bid >> 3;
    const int wgid = (xcd < r ? xcd * (q + 1) : r * (q + 1) + (xcd - r) * q) + slot;
    const int mt = wgid / Ntl, ntl = wgid - mt * Ntl;
    const int m0 = mt * 256, n0 = ntl * 128;

    f32x4 acc[8][2] = {};

#define G_STAGE(Asb, Bsb, kt) do {                                             \
    _Pragma("unroll")                                                          \
    for (int i_ = 0; i_ < 4; ++i_) {                                           \
        int ch_ = i_ * 512 + tid; int rw_ = ch_ >> 3, cc_ = ch_ & 7;           \
        int gc_ = cc_ ^ (rw_ & 7);                                             \
        gl16(A + (size_t)(m0 + rw_) * K + (kt) * 64 + gc_ * 8, Asb + ch_ * 16);\
    }                                                                          \
    _Pragma("unroll")                                                          \
    for (int i_ = 0; i_ < 2; ++i_) {                                           \
        int ch_ = i_ * 512 + tid; int rw_ = ch_ >> 3, cc_ = ch_ & 7;           \
        int gc_ = cc_ ^ (rw_ & 7);                                             \
        gl16(Bt + (size_t)(n0 + rw_) * K + (kt) * 64 + gc_ * 8, Bsb + ch_ * 16);\
    }                                                                          \
} while (0)

#define G_WAITN() do {                                                         \
    __builtin_amdgcn_sched_barrier(0);                                         \
    asm volatile("s_waitcnt vmcnt(6)" ::: "memory");                           \
    __builtin_amdgcn_s_barrier();                                              \
    __builtin_amdgcn_sched_barrier(0);                                         \
} while (0)

#define G_WAIT0() do {                                                         \
    __builtin_amdgcn_sched_barrier(0);                                         \
    asm volatile("s_waitcnt vmcnt(0)" ::: "memory");                           \
    __builtin_amdgcn_s_barrier();                                              \
    __builtin_amdgcn_sched_barrier(0);                                         \
} while (0)

#define G_ENDBAR() do {                                                        \
    __builtin_amdgcn_sched_barrier(0);                                         \
    __builtin_amdgcn_s_barrier();                                              \
    __builtin_amdgcn_sched_barrier(0);                                         \
} while (0)

#define G_COMPUTE(Asb, Bsb) do {                                               \
    _Pragma("unroll")                                                          \
    for (int kf_ = 0; kf_ < 2; ++kf_) {                                        \
        bf16x8 av_[8]; bf16x8 bv_[2];                                          \
        _Pragma("unroll")                                                      \
        for (int nf_ = 0; nf_ < 2; ++nf_) {                                    \
            int rw_ = wc * 32 + nf_ * 16 + l15;                                \
            bv_[nf_] = *(const bf16x8*)(Bsb + rw_ * 128 +                      \
                           (((kf_ * 4 + lg) ^ (rw_ & 7)) * 16));               \
        }                                                                      \
        _Pragma("unroll")                                                      \
        for (int mf_ = 0; mf_ < 8; ++mf_) {                                    \
            int rw_ = wr * 128 + mf_ * 16 + l15;                               \
            av_[mf_] = *(const bf16x8*)(Asb + rw_ * 128 +                      \
                           (((kf_ * 4 + lg) ^ (rw_ & 7)) * 16));               \
        }                                                                      \
        __builtin_amdgcn_s_setprio(1);                                         \
        _Pragma("unroll")                                                      \
        for (int mf_ = 0; mf_ < 8; ++mf_) {                                    \
            _Pragma("unroll")                                                  \
            for (int nf_ = 0; nf_ < 2; ++nf_) {                                \
                acc[mf_][nf_] = __builtin_amdgcn_mfma_f32_16x16x32_bf16(       \
                    av_[mf_], bv_[nf_], acc[mf_][nf_], 0, 0, 0);               \
            }                                                                  \
        }                                                                      \
        __builtin_amdgcn_s_setprio(0);                                         \
    }                                                                          \
} while (0)

    G_STAGE(As0, Bs0, 0);
    const int nt = K >> 6;                      // 8 or 32, always even
    for (int t = 0; t + 2 < nt; t += 2) {
        G_STAGE(As1, Bs1, t + 1);
        G_WAITN();
        G_COMPUTE(As0, Bs0);
        G_ENDBAR();
        G_STAGE(As0, Bs0, t + 2);
        G_WAITN();
        G_COMPUTE(As1, Bs1);
        G_ENDBAR();
    }
    G_STAGE(As1, Bs1, nt - 1);
    G_WAITN();
    G_COMPUTE(As0, Bs0);
    G_WAIT0();
    G_COMPUTE(As1, Bs1);

#undef G_STAGE
#undef G_WAITN
#undef G_WAIT0
#undef G_ENDBAR
#undef G_COMPUTE

    // epilogue: C/D layout col = lane&15, row = (lane>>4)*4 + j
#pragma unroll
    for (int nf = 0; nf < 2; ++nf) {
        int col = n0 + wc * 32 + nf * 16 + l15;
        float bvv = bias[col];
#pragma unroll
        for (int mf = 0; mf < 8; ++mf) {
#pragma unroll
            for (int j = 0; j < 4; ++j) {
                int row = m0 + wr * 128 + mf * 16 + lg * 4 + j;
                if (row < Mrows) {
                    float x = acc[mf][nf][j] + bvv;
                    if (MODE == 1) x = fmaxf(x, 0.f);
                    Cb[(size_t)row * N + col] = __float2bfloat16(x);
                }
            }
        }
    }
}

// ---------------- attention: MFMA, one block per (b,h) ----------------------
#define VP_ 168
__global__ __launch_bounds__(256, 2)
void attn_kernel(const bf16* __restrict__ qkv, const int* __restrict__ mask,
                 bf16* __restrict__ obf) {
    __shared__ alignas(16) unsigned short ldsbuf[32064];
    unsigned short* Kb = ldsbuf;                       // 10240 u16
    unsigned short* QP = ldsbuf + 10240;               // 10752 u16 (Q 10240 / Pb 10752)
    unsigned short* Vt = ldsbuf + 10240 + 10752;       // 10752 u16, [64][168]
    float* biasf = (float*)(ldsbuf + 10240 + 10752 + 10752);  // 160 f32

    const int bh = blockIdx.x;
    const int b = bh >> 3, h = bh & 7;
    const int tid = threadIdx.x, w = tid >> 6, lane = tid & 63;
    const int l15 = lane & 15, lg = lane >> 4;
    const size_t base = (size_t)b * S_ * 1536 + h * 64;
    const unsigned short* qk16 = (const unsigned short*)qkv;

    for (int i = tid; i < 160 * 8; i += 256) {
        int r = i >> 3, c = i & 7;
        int csw = c ^ (r & 7);
        uint4 kz = make_uint4(0u, 0u, 0u, 0u), qz = kz;
        if (r < 151) {
            kz = *(const uint4*)(qk16 + base + (size_t)r * 1536 + 512 + c * 8);
            qz = *(const uint4*)(qk16 + base + (size_t)r * 1536 + c * 8);
        }
        *(uint4*)((char*)Kb + r * 128 + csw * 16) = kz;
        *(uint4*)((char*)QP + r * 128 + csw * 16) = qz;
    }
    for (int i = tid; i < 160 * 8; i += 256) {
        int n = i >> 3, c = i & 7;
        u16x8 vv = {0, 0, 0, 0, 0, 0, 0, 0};
        if (n < 151) vv = *(const u16x8*)(qk16 + base + (size_t)n * 1536 + 1024 + c * 8);
#pragma unroll
        for (int e = 0; e < 8; ++e) Vt[(c * 8 + e) * VP_ + n] = vv[e];
    }
    if (tid < 160) {
        float bv;
        if (tid == 0) bv = 0.f;
        else if (tid <= 150) bv = (mask[b * T_ + tid - 1] != 0) ? 0.f : -1e9f;
        else bv = -1e9f;
        biasf[tid] = bv;
    }
    __syncthreads();

    int r0 = w * 16 + l15;
    int r1 = r0 + 64;
    int r2 = r0 + 128; if (r2 > 159) r2 = 159;
    bf16x8 q00 = *(const bf16x8*)((const char*)QP + r0 * 128 + ((lg)     ^ (r0 & 7)) * 16);
    bf16x8 q01 = *(const bf16x8*)((const char*)QP + r0 * 128 + ((4 + lg) ^ (r0 & 7)) * 16);
    bf16x8 q10 = *(const bf16x8*)((const char*)QP + r1 * 128 + ((lg)     ^ (r1 & 7)) * 16);
    bf16x8 q11 = *(const bf16x8*)((const char*)QP + r1 * 128 + ((4 + lg) ^ (r1 & 7)) * 16);
    bf16x8 q20 = *(const bf16x8*)((const char*)QP + r2 * 128 + ((lg)     ^ (r2 & 7)) * 16);
    bf16x8 q21 = *(const bf16x8*)((const char*)QP + r2 * 128 + ((4 + lg) ^ (r2 & 7)) * 16);
    float bc0 = biasf[l15],       bc1 = biasf[16 + l15],  bc2 = biasf[32 + l15];
    float bc3 = biasf[48 + l15],  bc4 = biasf[64 + l15],  bc5 = biasf[80 + l15];
    float bc6 = biasf[96 + l15],  bc7 = biasf[112 + l15], bc8 = biasf[128 + l15];
    float bc9 = biasf[144 + l15];
    __syncthreads();   // QP now becomes the per-wave P buffer

    bf16* Pw = (bf16*)(QP + w * 16 * VP_);
    const float scale = 0.125f;

#pragma unroll
    for (int mi = 0; mi < 3; ++mi) {
        int mt = w + mi * 4;
        if (mt < 10) {
            bf16x8 qk0 = (mi == 0) ? q00 : (mi == 1) ? q10 : q20;
            bf16x8 qk1 = (mi == 0) ? q01 : (mi == 1) ? q11 : q21;
            f32x4 sc[10] = {};
#pragma unroll
            for (int nt = 0; nt < 10; ++nt) {
                int kr = nt * 16 + l15;
                bf16x8 kb0 = *(const bf16x8*)((const char*)Kb + kr * 128 + ((lg)     ^ (kr & 7)) * 16);
                bf16x8 kb1 = *(const bf16x8*)((const char*)Kb + kr * 128 + ((4 + lg) ^ (kr & 7)) * 16);
                sc[nt] = __builtin_amdgcn_mfma_f32_16x16x32_bf16(qk0, kb0, sc[nt], 0, 0, 0);
                sc[nt] = __builtin_amdgcn_mfma_f32_16x16x32_bf16(qk1, kb1, sc[nt], 0, 0, 0);
            }
            float m0r = -3e38f, m1r = -3e38f, m2r = -3e38f, m3r = -3e38f;
#pragma unroll
            for (int nt = 0; nt < 10; ++nt) {
                float bv = (nt == 0) ? bc0 : (nt == 1) ? bc1 : (nt == 2) ? bc2 :
                           (nt == 3) ? bc3 : (nt == 4) ? bc4 : (nt == 5) ? bc5 :
                           (nt == 6) ? bc6 : (nt == 7) ? bc7 : (nt == 8) ? bc8 : bc9;
                sc[nt][0] = sc[nt][0] * scale + bv;  m0r = fmaxf(m0r, sc[nt][0]);
                sc[nt][1] = sc[nt][1] * scale + bv;  m1r = fmaxf(m1r, sc[nt][1]);
                sc[nt][2] = sc[nt][2] * scale + bv;  m2r = fmaxf(m2r, sc[nt][2]);
                sc[nt][3] = sc[nt][3] * scale + bv;  m3r = fmaxf(m3r, sc[nt][3]);
            }
#pragma unroll
            for (int off = 1; off < 16; off <<= 1) {
                m0r = fmaxf(m0r, __shfl_xor(m0r, off));
                m1r = fmaxf(m1r, __shfl_xor(m1r, off));
                m2r = fmaxf(m2r, __shfl_xor(m2r, off));
                m3r = fmaxf(m3r, __shfl_xor(m3r, off));
            }
            float s0 = 0.f, s1 = 0.f, s2 = 0.f, s3 = 0.f;
#pragma unroll
            for (int nt = 0; nt < 10; ++nt) {
                sc[nt][0] = __expf(sc[nt][0] - m0r);  s0 += sc[nt][0];
                sc[nt][1] = __expf(sc[nt][1] - m1r);  s1 += sc[nt][1];
                sc[nt][2] = __expf(sc[nt][2] - m2r);  s2 += sc[nt][2];
                sc[nt][3] = __expf(sc[nt][3] - m3r);  s3 += sc[nt][3];
            }
#pragma unroll
            for (int off = 1; off < 16; off <<= 1) {
                s0 += __shfl_xor(s0, off);
                s1 += __shfl_xor(s1, off);
                s2 += __shfl_xor(s2, off);
                s3 += __shfl_xor(s3, off);
            }
            s0 = 1.f / s0; s1 = 1.f / s1; s2 = 1.f / s2; s3 = 1.f / s3;
#pragma unroll
            for (int nt = 0; nt < 10; ++nt) {
                int cb = nt * 16 + l15;
                Pw[(lg * 4 + 0) * VP_ + cb] = __float2bfloat16(sc[nt][0]);
                Pw[(lg * 4 + 1) * VP_ + cb] = __float2bfloat16(sc[nt][1]);
                Pw[(lg * 4 + 2) * VP_ + cb] = __float2bfloat16(sc[nt][2]);
                Pw[(lg * 4 + 3) * VP_ + cb] = __float2bfloat16(sc[nt][3]);
            }
            f32x4 oc[4] = {};
#pragma unroll
            for (int nc = 0; nc < 5; ++nc) {
                bf16x8 pa = *(const bf16x8*)((const unsigned short*)Pw + l15 * VP_ + nc * 32 + lg * 8);
#pragma unroll
                for (int dt = 0; dt < 4; ++dt) {
                    bf16x8 vb = *(const bf16x8*)(Vt + (dt * 16 + l15) * VP_ + nc * 32 + lg * 8);
                    oc[dt] = __builtin_amdgcn_mfma_f32_16x16x32_bf16(pa, vb, oc[dt], 0, 0, 0);
                }
            }
            int orow = mt * 16 + lg * 4;
#pragma unroll
            for (int dt = 0; dt < 4; ++dt) {
                int d = h * 64 + dt * 16 + l15;
                if (orow + 0 < 151) obf[((size_t)(b * S_ + orow + 0)) * E_ + d] = __float2bfloat16(oc[dt][0] * s0);
                if (orow + 1 < 151) obf[((size_t)(b * S_ + orow + 1)) * E_ + d] = __float2bfloat16(oc[dt][1] * s1);
                if (orow + 2 < 151) obf[((size_t)(b * S_ + orow + 2)) * E_ + d] = __float2bfloat16(oc[dt][2] * s2);
                if (orow + 3 < 151) obf[((size_t)(b * S_ + orow + 3)) * E_ + d] = __float2bfloat16(oc[dt][3] * s3);
            }
        }
    }
}

// ---------------- fused residual + LayerNorm, bf16 stream (4 rows/block) -----
// x = LN(bf2f(xbf) + bf2f(t))*g + b -> xbf  (f32 math, bf16 storage)
__global__ __launch_bounds__(256)
void ln_res_kernel(const bf16* __restrict__ t_bf, const float* __restrict__ gw,
                   const float* __restrict__ bw, bf16* __restrict__ xbf) {
    int lane = threadIdx.x & 63;
    int row = blockIdx.x * 4 + (threadIdx.x >> 6);
    size_t o = (size_t)row * E_ + lane * 8;
    u16x8 xv = *(const u16x8*)((const unsigned short*)xbf + o);
    u16x8 tv = *(const u16x8*)((const unsigned short*)t_bf + o);
    f32x4 t0, t1;
    t0[0] = b2f(xv[0]) + b2f(tv[0]); t0[1] = b2f(xv[1]) + b2f(tv[1]);
    t0[2] = b2f(xv[2]) + b2f(tv[2]); t0[3] = b2f(xv[3]) + b2f(tv[3]);
    t1[0] = b2f(xv[4]) + b2f(tv[4]); t1[1] = b2f(xv[5]) + b2f(tv[5]);
    t1[2] = b2f(xv[6]) + b2f(tv[6]); t1[3] = b2f(xv[7]) + b2f(tv[7]);
    float s = t0[0] + t0[1] + t0[2] + t0[3] + t1[0] + t1[1] + t1[2] + t1[3];
#pragma unroll
    for (int off = 1; off < 64; off <<= 1) s += __shfl_xor(s, off);
    float mean = s * (1.0f / 512.0f);
    f32x4 d0 = t0 - mean, d1 = t1 - mean;
    float q = d0[0]*d0[0] + d0[1]*d0[1] + d0[2]*d0[2] + d0[3]*d0[3]
            + d1[0]*d1[0] + d1[1]*d1[1] + d1[2]*d1[2] + d1[3]*d1[3];
#pragma unroll
    for (int off = 1; off < 64; off <<= 1) q += __shfl_xor(q, off);
    float rstd = rsqrtf(q * (1.0f / 512.0f) + 1e-5f);
    f32x4 g0 = *(const f32x4*)(gw + lane * 8);
    f32x4 g1 = *(const f32x4*)(gw + lane * 8 + 4);
    f32x4 bb0 = *(const f32x4*)(bw + lane * 8);
    f32x4 bb1 = *(const f32x4*)(bw + lane * 8 + 4);
    f32x4 y0 = d0 * rstd * g0 + bb0;
    f32x4 y1 = d1 * rstd * g1 + bb1;
    union { unsigned short s[8]; uint4 v; } pk;
    pk.s[0] = f2b(y0[0]); pk.s[1] = f2b(y0[1]); pk.s[2] = f2b(y0[2]); pk.s[3] = f2b(y0[3]);
    pk.s[4] = f2b(y1[0]); pk.s[5] = f2b(y1[1]); pk.s[6] = f2b(y1[2]); pk.s[7] = f2b(y1[3]);
    *(uint4*)((unsigned short*)xbf + o) = pk.v;
}

// ---------------- final: out[b,:] = f32(xbf[b*S + 0, :]) ---------------------
__global__ __launch_bounds__(256)
void out_kernel(const bf16* __restrict__ xbf, float* __restrict__ out) {
    int i = blockIdx.x * 256 + threadIdx.x;
    int b = i >> 9, e = i & 511;
    out[i] = b2f(((const unsigned short*)xbf)[(size_t)b * S_ * E_ + e]);
}

extern "C" void kernel_launch(void* const* d_in, const int* in_sizes, int n_in,
                              void* d_out, int out_size, void* d_ws, size_t ws_size,
                              hipStream_t stream) {
    (void)in_sizes; (void)n_in; (void)out_size; (void)ws_size;
    const int*   token_type = (const int*)d_in[0];
    const int*   mask       = (const int*)d_in[1];
    const int*   dec_idx    = (const int*)d_in[2];
    const float* action_val = (const float*)d_in[3];
    const float* dis_val    = (const float*)d_in[4];
    const float* v_val      = (const float*)d_in[5];
    const float* action_W   = (const float*)d_in[6];
    const float* action_b   = (const float*)d_in[7];
    const float* dis_W      = (const float*)d_in[8];
    const float* dis_b      = (const float*)d_in[9];
    const float* v_W        = (const float*)d_in[10];
    const float* v_b        = (const float*)d_in[11];
    const float* dec_emb    = (const float*)d_in[12];
    const float* pos        = (const float*)d_in[13];
    const float* cls        = (const float*)d_in[14];
    const float* qkv_W      = (const float*)d_in[15];
    const float* qkv_b      = (const float*)d_in[16];
    const float* out_W      = (const float*)d_in[17];
    const float* out_b      = (const float*)d_in[18];
    const float* ln1_g      = (const float*)d_in[19];
    const float* ln1_b      = (const float*)d_in[20];
    const float* ff1_W      = (const float*)d_in[21];
    const float* ff1_b      = (const float*)d_in[22];
    const float* ff2_W      = (const float*)d_in[23];
    const float* ff2_b      = (const float*)d_in[24];
    const float* ln2_g      = (const float*)d_in[25];
    const float* ln2_b      = (const float*)d_in[26];

    // allow 96KB dynamic LDS for the pipelined GEMM (host-side, capture-safe)
    hipFuncSetAttribute(reinterpret_cast<const void*>(gemm256_kernel<3>),
                        hipFuncAttributeMaxDynamicSharedMemorySize, 98304);
    hipFuncSetAttribute(reinterpret_cast<const void*>(gemm256_kernel<1>),
                        hipFuncAttributeMaxDynamicSharedMemorySize, 98304);

    // ---- workspace: ~236 MB; xbf BEFORE arena so A-staging over-reads of the
    // partial last m-tile (<=256 rows * 512 * 2B) land in owned memory.
    char* ws = (char*)d_ws;
    size_t off = 0;
    auto alloc = [&](size_t bytes) {
        char* p = ws + off;
        off += (bytes + 255) & ~(size_t)255;
        return p;
    };
    bf16* qkvT = (bf16*)alloc((size_t)L_ * 1536 * 512 * 2);  //  9.4 MB
    bf16* outT = (bf16*)alloc((size_t)L_ * 512 * 512 * 2);   //  3.1 MB
    bf16* ff1T = (bf16*)alloc((size_t)L_ * 2048 * 512 * 2);  // 12.6 MB
    bf16* ff2T = (bf16*)alloc((size_t)L_ * 512 * 2048 * 2);  // 12.6 MB
    bf16*  xbf = (bf16*)alloc((size_t)M_ * E_ * 2);          // 39.6 MB bf16 residual x
    bf16* arena = (bf16*)alloc((size_t)M_ * 2048 * 2);       // 158.3 MB shared scratch
    bf16* qkvbf  = arena;                                    // M*1536 (qkv out)
    bf16* obf    = arena + (size_t)M_ * 1536;                // M*512 (attn out)
    bf16* projout= arena;                                    // M*512 (proj out)
    bf16* hbf    = arena + (size_t)M_ * 512;                 // half-M*2048 (ff1 out)
    bf16* t2     = arena + (size_t)M_ * 1536;                // half-M*512 (ff2 out)

    dim3 blk(256);
    transpose_cast_kernel<<<dim3(8, 24, L_), blk, 0, stream>>>(qkv_W, qkvT, 512, 1536);
    transpose_cast_kernel<<<dim3(8, 8,  L_), blk, 0, stream>>>(out_W, outT, 512, 512);
    transpose_cast_kernel<<<dim3(8, 32, L_), blk, 0, stream>>>(ff1_W, ff1T, 512, 2048);
    transpose_cast_kernel<<<dim3(32, 8, L_), blk, 0, stream>>>(ff2_W, ff2T, 2048, 512);

    embed_kernel<<<dim3(M_ / 4), blk, 0, stream>>>(token_type, dec_idx, action_val, dis_val, v_val,
        action_W, action_b, dis_W, dis_b, v_W, v_b, dec_emb, pos, cls, xbf);

    const int HALF_ROWS = 19328;   // 75.5 m-tiles of 256 -> 76 clamped

    for (int l = 0; l < L_; ++l) {
        const bf16* qT = qkvT + (size_t)l * 1536 * 512;
        const bf16* oT = outT + (size_t)l * 512 * 512;
        const bf16* f1 = ff1T + (size_t)l * 2048 * 512;
        const bf16* f2 = ff2T + (size_t)l * 512 * 2048;

        // QKV (full M, 151 exact m-tiles) -> qkvbf; attention -> obf
        gemm256_kernel<3><<<dim3(151 * 12), dim3(512), 98304, stream>>>(
            xbf, qT, qkv_b + l * 1536, qkvbf, M_, 1536, 512);
        attn_kernel<<<dim3(B_ * H_), blk, 0, stream>>>(qkvbf, mask, obf);
        // proj (full M) -> projout; fused res+LN1 updates xbf in place
        gemm256_kernel<3><<<dim3(151 * 4), dim3(512), 98304, stream>>>(
            obf, oT, out_b + l * 512, projout, M_, 512, 512);
        ln_res_kernel<<<dim3(M_ / 4), blk, 0, stream>>>(
            projout, ln1_g + l * 512, ln1_b + l * 512, xbf);
        // FF, 2 half-chunks: ff1 -> hbf, ff2 -> t2, res+LN2 updates xbf
        for (int c = 0; c < 2; ++c) {
            size_t rb = (size_t)c * HALF_ROWS;
            gemm256_kernel<1><<<dim3(76 * 16), dim3(512), 98304, stream>>>(
                xbf + rb * E_, f1, ff1_b + l * 2048, hbf, HALF_ROWS, 2048, 512);
            gemm256_kernel<3><<<dim3(76 * 4), dim3(512), 98304, stream>>>(
                hbf, f2, ff2_b + l * 512, t2, HALF_ROWS, 512, 2048);
            ln_res_kernel<<<dim3(HALF_ROWS / 4), blk, 0, stream>>>(
                t2, ln2_g + l * 512, ln2_b + l * 512, xbf + rb * E_);
        }
    }
    out_kernel<<<dim3(B_ * E_ / 256), blk, 0, stream>>>(xbf, (float*)d_out);
}

// Round 10
// 3210.743 us; speedup vs baseline: 1.1456x; 1.1456x over previous
//
#include <hip/hip_runtime.h>
#include <hip/hip_bf16.h>
#include <stdint.h>

#define B_ 256
#define T_ 150
#define S_ 151
#define E_ 512
#define H_ 8
#define L_ 6
#define FF_ 2048
#define M_ (B_*S_)   // 38656 = 302*128 = 151*256

typedef __hip_bfloat16 bf16;
typedef __bf16 bf16x8 __attribute__((ext_vector_type(8)));
typedef float f32x4 __attribute__((ext_vector_type(4)));
typedef unsigned short u16x8 __attribute__((ext_vector_type(8)));

__device__ inline unsigned short f2b(float x) {
    union { __hip_bfloat16 h; unsigned short u; } c;
    c.h = __float2bfloat16(x);
    return c.u;
}
__device__ inline float b2f(unsigned short u) {
    union { uint32_t u; float f; } c;
    c.u = (uint32_t)u << 16;
    return c.f;
}

// async global->LDS 16B; LDS dest must be wave-uniform base + lane*16 (linear)
__device__ __forceinline__ void gl16(const void* g, void* l) {
    __builtin_amdgcn_global_load_lds(
        (const __attribute__((address_space(1))) unsigned int*)g,
        (__attribute__((address_space(3))) unsigned int*)l, 16, 0, 0);
}

// ---------------- weight transpose f32[K][N] -> bf16[N][K], batched over L ----
__global__ __launch_bounds__(256)
void transpose_cast_kernel(const float* __restrict__ src, bf16* __restrict__ dst,
                           int K, int N) {
    __shared__ float tile[64][65];
    int l = blockIdx.z;
    const float* s = src + (size_t)l * K * N;
    bf16* d = dst + (size_t)l * K * N;
    int bk = blockIdx.x * 64, bn = blockIdx.y * 64;
    int col = threadIdx.x & 63, rg = threadIdx.x >> 6;
#pragma unroll
    for (int i = 0; i < 16; ++i) {
        int r = i * 4 + rg;
        tile[r][col] = s[(size_t)(bk + r) * N + bn + col];
    }
    __syncthreads();
#pragma unroll
    for (int i = 0; i < 16; ++i) {
        int r = i * 4 + rg;
        d[(size_t)(bn + r) * K + bk + col] = __float2bfloat16(tile[col][r]);
    }
}

// ---------------- token embedding + pos + cls -> xbf (4 rows/block) ----------
__global__ __launch_bounds__(256)
void embed_kernel(const int* __restrict__ tt, const int* __restrict__ dec_idx,
                  const float* __restrict__ action_val, const float* __restrict__ dis_val,
                  const float* __restrict__ v_val,
                  const float* __restrict__ action_W, const float* __restrict__ action_b,
                  const float* __restrict__ dis_W, const float* __restrict__ dis_b,
                  const float* __restrict__ v_W, const float* __restrict__ v_b,
                  const float* __restrict__ dec_emb, const float* __restrict__ pos,
                  const float* __restrict__ cls,
                  bf16* __restrict__ xbf) {
    int lane = threadIdx.x & 63;
    int bs = blockIdx.x * 4 + (threadIdx.x >> 6);
    int b = bs / S_, s = bs - b * S_;
    int e0 = lane * 8;
    f32x4 v0, v1;
    if (s == 0) {
        v0 = *(const f32x4*)(cls + e0);
        v1 = *(const f32x4*)(cls + e0 + 4);
    } else {
        int t = s - 1;
        int ty = tt[b * T_ + t];
        if (ty == 0) {
            float av = action_val[b * T_ + t];
            f32x4 w0 = *(const f32x4*)(action_W + e0);
            f32x4 w1 = *(const f32x4*)(action_W + e0 + 4);
            f32x4 b0 = *(const f32x4*)(action_b + e0);
            f32x4 b1 = *(const f32x4*)(action_b + e0 + 4);
            v0 = w0 * av + b0;  v1 = w1 * av + b1;
        } else if (ty == 1) {
            v0 = *(const f32x4*)(dis_b + e0) + *(const f32x4*)(v_b + e0);
            v1 = *(const f32x4*)(dis_b + e0 + 4) + *(const f32x4*)(v_b + e0 + 4);
#pragma unroll
            for (int i = 0; i < 10; ++i) {
                float dv = dis_val[(b * T_ + t) * 10 + i];
                v0 += *(const f32x4*)(dis_W + i * E_ + e0) * dv;
                v1 += *(const f32x4*)(dis_W + i * E_ + e0 + 4) * dv;
            }
#pragma unroll
            for (int i = 0; i < 3; ++i) {
                float vv = v_val[(b * T_ + t) * 3 + i];
                v0 += *(const f32x4*)(v_W + i * E_ + e0) * vv;
                v1 += *(const f32x4*)(v_W + i * E_ + e0 + 4) * vv;
            }
        } else {
            const float* de = dec_emb + (size_t)dec_idx[b * T_ + t] * E_;
            v0 = *(const f32x4*)(de + e0);
            v1 = *(const f32x4*)(de + e0 + 4);
        }
        v0 += *(const f32x4*)(pos + (size_t)t * E_ + e0);
        v1 += *(const f32x4*)(pos + (size_t)t * E_ + e0 + 4);
    }
    size_t o = (size_t)bs * E_ + e0;
    union { unsigned short s[8]; uint4 v; } pk;
    pk.s[0] = f2b(v0[0]); pk.s[1] = f2b(v0[1]); pk.s[2] = f2b(v0[2]); pk.s[3] = f2b(v0[3]);
    pk.s[4] = f2b(v1[0]); pk.s[5] = f2b(v1[1]); pk.s[6] = f2b(v1[2]); pk.s[7] = f2b(v1[3]);
    *(uint4*)((unsigned short*)xbf + o) = pk.v;
}

// ---------------- bf16 MFMA GEMM 128x128 (R7-proven, for proj/ff2) -----------
// MODE: 1 = relu(acc+bias) -> bf16 | 3 = acc+bias -> bf16
template<int MODE>
__global__ __launch_bounds__(256, 2)
void gemm_kernel(const bf16* __restrict__ A, const bf16* __restrict__ Bt,
                 const float* __restrict__ bias, bf16* __restrict__ Cb,
                 int N, int K) {
    __shared__ alignas(16) bf16 As[128][64];
    __shared__ alignas(16) bf16 Bs[128][64];
    const int tid = threadIdx.x;
    const int wave = tid >> 6, lane = tid & 63;
    const int nwg = gridDim.x, bid = blockIdx.x;
    const int Nt = N >> 7;
    const int q = nwg >> 3, r = nwg & 7;
    const int xcd = bid & 7, slot = bid >> 3;
    const int wgid = (xcd < r ? xcd * (q + 1) : r * (q + 1) + (xcd - r) * q) + slot;
    const int mt = wgid / Nt, ntl = wgid - mt * Nt;
    const int m0 = mt * 128, n0 = ntl * 128;
    const int wm = (wave >> 1) * 64, wn = (wave & 1) * 64;
    const int l15 = lane & 15, lg = lane >> 4;

    f32x4 acc[4][4] = {};

    for (int k0 = 0; k0 < K; k0 += 64) {
#pragma unroll
        for (int i = 0; i < 4; ++i) {
            int chunk = i * 256 + tid;      // 0..1023
            int row = chunk >> 3, cl = chunk & 7;
            int gc = cl ^ (row & 7);
            gl16(A + (size_t)(m0 + row) * K + k0 + gc * 8,
                 (char*)&As[0][0] + chunk * 16);
            gl16(Bt + (size_t)(n0 + row) * K + k0 + gc * 8,
                 (char*)&Bs[0][0] + chunk * 16);
        }
        __syncthreads();
#pragma unroll
        for (int kf = 0; kf < 2; ++kf) {
            bf16x8 af[4], bfr[4];
#pragma unroll
            for (int mf = 0; mf < 4; ++mf) {
                int row = wm + mf * 16 + l15;
                int csw = (kf * 4 + lg) ^ (row & 7);
                af[mf] = *(const bf16x8*)((const char*)&As[0][0] + row * 128 + csw * 16);
            }
#pragma unroll
            for (int nf = 0; nf < 4; ++nf) {
                int row = wn + nf * 16 + l15;
                int csw = (kf * 4 + lg) ^ (row & 7);
                bfr[nf] = *(const bf16x8*)((const char*)&Bs[0][0] + row * 128 + csw * 16);
            }
#pragma unroll
            for (int mf = 0; mf < 4; ++mf)
#pragma unroll
                for (int nf = 0; nf < 4; ++nf)
                    acc[mf][nf] = __builtin_amdgcn_mfma_f32_16x16x32_bf16(
                        af[mf], bfr[nf], acc[mf][nf], 0, 0, 0);
        }
        __syncthreads();
    }
#pragma unroll
    for (int nf = 0; nf < 4; ++nf) {
        int col = n0 + wn + nf * 16 + l15;
        float bv = bias[col];
#pragma unroll
        for (int mf = 0; mf < 4; ++mf) {
#pragma unroll
            for (int j = 0; j < 4; ++j) {
                int row = m0 + wm + mf * 16 + lg * 4 + j;
                size_t idx = (size_t)row * N + col;
                float x = acc[mf][nf][j] + bv;
                if (MODE == 1) x = fmaxf(x, 0.f);
                Cb[idx] = __float2bfloat16(x);
            }
        }
    }
}

// ---------------- 256x256 bf16 MFMA GEMM, 4-phase staggered prefetch ---------
// See R8/R9 analysis. Buffers selected via scalar ternaries (no pointer array
// of LDS addrspacecasts — that failed to compile on gfx950).
// MODE: 1 = relu(acc+bias) | 3 = acc+bias
template<int MODE>
__global__ __launch_bounds__(512, 1)
void gemm8p_kernel(const bf16* __restrict__ A, const bf16* __restrict__ Bt,
                   const float* __restrict__ bias, bf16* __restrict__ Cb,
                   int Mrows, int N, int K) {
    extern __shared__ char smem[];

    const int tid = threadIdx.x;
    const int w = tid >> 6, lane = tid & 63;
    const int l15 = lane & 15, lg = lane >> 4;
    const int wr = w >> 2, wc = w & 3;

    const int nwg = gridDim.x, bid = blockIdx.x;
    const int Ntl = N >> 8;
    const int q = nwg >> 3, r = nwg & 7;
    const int xcd = bid & 7, slot = bid >> 3;
    const int wgid = (xcd < r ? xcd * (q + 1) : r * (q + 1) + (xcd - r) * q) + slot;
    const int mt = wgid / Ntl, ntl = wgid - mt * Ntl;
    const int m0 = mt * 256, n0 = ntl * 256;

    // swizzle byte offsets (row&7 == l15&7 for all frag rows)
    const int sw0 = ((lg) ^ (l15 & 7)) * 16;
    const int sw1 = ((4 + lg) ^ (l15 & 7)) * 16;

    f32x4 acc[8][4] = {};

    // stage one half-tile (128 rows) of src into dst: 2 gl16/thread
#define SG_HALF(src, dst, kt, h) do {                                          \
    _Pragma("unroll")                                                          \
    for (int i_ = 0; i_ < 2; ++i_) {                                           \
        int ch_ = (h) * 1024 + i_ * 512 + tid;                                 \
        int rw_ = ch_ >> 3, cc_ = ch_ & 7;                                     \
        int gc_ = cc_ ^ (rw_ & 7);                                             \
        gl16(src + (size_t)rw_ * K + (kt) * 64 + gc_ * 8, dst + ch_ * 16);     \
    }                                                                          \
} while (0)

#define LOAD_A(buf, mfB) do {                                                  \
    _Pragma("unroll")                                                          \
    for (int ml_ = 0; ml_ < 4; ++ml_) {                                        \
        int rw_ = wr * 128 + ((mfB) + ml_) * 16 + l15;                         \
        av[ml_ * 2 + 0] = *(const bf16x8*)((buf) + rw_ * 128 + sw0);           \
        av[ml_ * 2 + 1] = *(const bf16x8*)((buf) + rw_ * 128 + sw1);           \
    }                                                                          \
} while (0)

#define LOAD_B(buf, nfB) do {                                                  \
    _Pragma("unroll")                                                          \
    for (int nl_ = 0; nl_ < 2; ++nl_) {                                        \
        int rw_ = wc * 64 + ((nfB) + nl_) * 16 + l15;                          \
        bv[nl_ * 2 + 0] = *(const bf16x8*)((buf) + rw_ * 128 + sw0);           \
        bv[nl_ * 2 + 1] = *(const bf16x8*)((buf) + rw_ * 128 + sw1);           \
    }                                                                          \
} while (0)

#define MM(mfB, nfB) do {                                                      \
    __builtin_amdgcn_s_setprio(1);                                             \
    _Pragma("unroll")                                                          \
    for (int ml_ = 0; ml_ < 4; ++ml_) {                                        \
        _Pragma("unroll")                                                      \
        for (int nl_ = 0; nl_ < 2; ++nl_) {                                    \
            _Pragma("unroll")                                                  \
            for (int kf_ = 0; kf_ < 2; ++kf_) {                                \
                acc[(mfB) + ml_][(nfB) + nl_] =                                \
                    __builtin_amdgcn_mfma_f32_16x16x32_bf16(                   \
                        av[ml_ * 2 + kf_], bv[nl_ * 2 + kf_],                  \
                        acc[(mfB) + ml_][(nfB) + nl_], 0, 0, 0);               \
            }                                                                  \
        }                                                                      \
    }                                                                          \
    __builtin_amdgcn_s_setprio(0);                                             \
} while (0)

    const bf16* Ab = A + (size_t)m0 * K;
    const bf16* Bb = Bt + (size_t)n0 * K;
    // prologue: full tile 0 into buf 0
    {
        char* A0 = smem;
        char* B0 = smem + 65536;
        SG_HALF(Ab, A0, 0, 0); SG_HALF(Ab, A0, 0, 1);
        SG_HALF(Bb, B0, 0, 0); SG_HALF(Bb, B0, 0, 1);
    }

    const int nt = K >> 6;
    for (int t = 0; t < nt; ++t) {
        const int cur = t & 1, nxt = cur ^ 1;
        const char* cA = smem + cur * 32768;
        const char* cB = smem + 65536 + cur * 32768;
        char* nA = smem + nxt * 32768;
        char* nB = smem + 65536 + nxt * 32768;
        const bool st = (t + 1 < nt);

        __builtin_amdgcn_sched_barrier(0);
        asm volatile("s_waitcnt vmcnt(0)" ::: "memory");
        __builtin_amdgcn_s_barrier();
        __builtin_amdgcn_sched_barrier(0);

        bf16x8 av[8], bv[4];
        // phase 0: mf0-3 x nf0-1
        if (st) SG_HALF(Ab, nA, t + 1, 0);
        LOAD_A(cA, 0);
        LOAD_B(cB, 0);
        MM(0, 0);
        __builtin_amdgcn_sched_barrier(0);
        // phase 1: mf0-3 x nf2-3 (A held)
        if (st) SG_HALF(Ab, nA, t + 1, 1);
        LOAD_B(cB, 2);
        MM(0, 2);
        __builtin_amdgcn_sched_barrier(0);
        // phase 2: mf4-7 x nf2-3 (B held)
        if (st) SG_HALF(Bb, nB, t + 1, 0);
        LOAD_A(cA, 4);
        MM(4, 2);
        __builtin_amdgcn_sched_barrier(0);
        // phase 3: mf4-7 x nf0-1 (A held)
        if (st) SG_HALF(Bb, nB, t + 1, 1);
        LOAD_B(cB, 0);
        MM(4, 0);
        __builtin_amdgcn_sched_barrier(0);
    }

#undef SG_HALF
#undef LOAD_A
#undef LOAD_B
#undef MM

    // epilogue: C/D layout col = lane&15, row = (lane>>4)*4 + j
#pragma unroll
    for (int nf = 0; nf < 4; ++nf) {
        int col = n0 + wc * 64 + nf * 16 + l15;
        float bvv = bias[col];
#pragma unroll
        for (int mf = 0; mf < 8; ++mf) {
#pragma unroll
            for (int j = 0; j < 4; ++j) {
                int row = m0 + wr * 128 + mf * 16 + lg * 4 + j;
                if (row < Mrows) {
                    float x = acc[mf][nf][j] + bvv;
                    if (MODE == 1) x = fmaxf(x, 0.f);
                    Cb[(size_t)row * N + col] = __float2bfloat16(x);
                }
            }
        }
    }
}

// ---------------- attention: MFMA, one block per (b,h) ----------------------
#define VP_ 168
__global__ __launch_bounds__(256, 2)
void attn_kernel(const bf16* __restrict__ qkv, const int* __restrict__ mask,
                 bf16* __restrict__ obf) {
    __shared__ alignas(16) unsigned short ldsbuf[32064];
    unsigned short* Kb = ldsbuf;                       // 10240 u16
    unsigned short* QP = ldsbuf + 10240;               // 10752 u16 (Q 10240 / Pb 10752)
    unsigned short* Vt = ldsbuf + 10240 + 10752;       // 10752 u16, [64][168]
    float* biasf = (float*)(ldsbuf + 10240 + 10752 + 10752);  // 160 f32

    const int bh = blockIdx.x;
    const int b = bh >> 3, h = bh & 7;
    const int tid = threadIdx.x, w = tid >> 6, lane = tid & 63;
    const int l15 = lane & 15, lg = lane >> 4;
    const size_t base = (size_t)b * S_ * 1536 + h * 64;
    const unsigned short* qk16 = (const unsigned short*)qkv;

    for (int i = tid; i < 160 * 8; i += 256) {
        int r = i >> 3, c = i & 7;
        int csw = c ^ (r & 7);
        uint4 kz = make_uint4(0u, 0u, 0u, 0u), qz = kz;
        if (r < 151) {
            kz = *(const uint4*)(qk16 + base + (size_t)r * 1536 + 512 + c * 8);
            qz = *(const uint4*)(qk16 + base + (size_t)r * 1536 + c * 8);
        }
        *(uint4*)((char*)Kb + r * 128 + csw * 16) = kz;
        *(uint4*)((char*)QP + r * 128 + csw * 16) = qz;
    }
    for (int i = tid; i < 160 * 8; i += 256) {
        int n = i >> 3, c = i & 7;
        u16x8 vv = {0, 0, 0, 0, 0, 0, 0, 0};
        if (n < 151) vv = *(const u16x8*)(qk16 + base + (size_t)n * 1536 + 1024 + c * 8);
#pragma unroll
        for (int e = 0; e < 8; ++e) Vt[(c * 8 + e) * VP_ + n] = vv[e];
    }
    if (tid < 160) {
        float bv;
        if (tid == 0) bv = 0.f;
        else if (tid <= 150) bv = (mask[b * T_ + tid - 1] != 0) ? 0.f : -1e9f;
        else bv = -1e9f;
        biasf[tid] = bv;
    }
    __syncthreads();

    int r0 = w * 16 + l15;
    int r1 = r0 + 64;
    int r2 = r0 + 128; if (r2 > 159) r2 = 159;
    bf16x8 q00 = *(const bf16x8*)((const char*)QP + r0 * 128 + ((lg)     ^ (r0 & 7)) * 16);
    bf16x8 q01 = *(const bf16x8*)((const char*)QP + r0 * 128 + ((4 + lg) ^ (r0 & 7)) * 16);
    bf16x8 q10 = *(const bf16x8*)((const char*)QP + r1 * 128 + ((lg)     ^ (r1 & 7)) * 16);
    bf16x8 q11 = *(const bf16x8*)((const char*)QP + r1 * 128 + ((4 + lg) ^ (r1 & 7)) * 16);
    bf16x8 q20 = *(const bf16x8*)((const char*)QP + r2 * 128 + ((lg)     ^ (r2 & 7)) * 16);
    bf16x8 q21 = *(const bf16x8*)((const char*)QP + r2 * 128 + ((4 + lg) ^ (r2 & 7)) * 16);
    float bc0 = biasf[l15],       bc1 = biasf[16 + l15],  bc2 = biasf[32 + l15];
    float bc3 = biasf[48 + l15],  bc4 = biasf[64 + l15],  bc5 = biasf[80 + l15];
    float bc6 = biasf[96 + l15],  bc7 = biasf[112 + l15], bc8 = biasf[128 + l15];
    float bc9 = biasf[144 + l15];
    __syncthreads();   // QP now becomes the per-wave P buffer

    bf16* Pw = (bf16*)(QP + w * 16 * VP_);
    const float scale = 0.125f;

#pragma unroll
    for (int mi = 0; mi < 3; ++mi) {
        int mt = w + mi * 4;
        if (mt < 10) {
            bf16x8 qk0 = (mi == 0) ? q00 : (mi == 1) ? q10 : q20;
            bf16x8 qk1 = (mi == 0) ? q01 : (mi == 1) ? q11 : q21;
            f32x4 sc[10] = {};
#pragma unroll
            for (int nt = 0; nt < 10; ++nt) {
                int kr = nt * 16 + l15;
                bf16x8 kb0 = *(const bf16x8*)((const char*)Kb + kr * 128 + ((lg)     ^ (kr & 7)) * 16);
                bf16x8 kb1 = *(const bf16x8*)((const char*)Kb + kr * 128 + ((4 + lg) ^ (kr & 7)) * 16);
                sc[nt] = __builtin_amdgcn_mfma_f32_16x16x32_bf16(qk0, kb0, sc[nt], 0, 0, 0);
                sc[nt] = __builtin_amdgcn_mfma_f32_16x16x32_bf16(qk1, kb1, sc[nt], 0, 0, 0);
            }
            float m0r = -3e38f, m1r = -3e38f, m2r = -3e38f, m3r = -3e38f;
#pragma unroll
            for (int nt = 0; nt < 10; ++nt) {
                float bv = (nt == 0) ? bc0 : (nt == 1) ? bc1 : (nt == 2) ? bc2 :
                           (nt == 3) ? bc3 : (nt == 4) ? bc4 : (nt == 5) ? bc5 :
                           (nt == 6) ? bc6 : (nt == 7) ? bc7 : (nt == 8) ? bc8 : bc9;
                sc[nt][0] = sc[nt][0] * scale + bv;  m0r = fmaxf(m0r, sc[nt][0]);
                sc[nt][1] = sc[nt][1] * scale + bv;  m1r = fmaxf(m1r, sc[nt][1]);
                sc[nt][2] = sc[nt][2] * scale + bv;  m2r = fmaxf(m2r, sc[nt][2]);
                sc[nt][3] = sc[nt][3] * scale + bv;  m3r = fmaxf(m3r, sc[nt][3]);
            }
#pragma unroll
            for (int off = 1; off < 16; off <<= 1) {
                m0r = fmaxf(m0r, __shfl_xor(m0r, off));
                m1r = fmaxf(m1r, __shfl_xor(m1r, off));
                m2r = fmaxf(m2r, __shfl_xor(m2r, off));
                m3r = fmaxf(m3r, __shfl_xor(m3r, off));
            }
            float s0 = 0.f, s1 = 0.f, s2 = 0.f, s3 = 0.f;
#pragma unroll
            for (int nt = 0; nt < 10; ++nt) {
                sc[nt][0] = __expf(sc[nt][0] - m0r);  s0 += sc[nt][0];
                sc[nt][1] = __expf(sc[nt][1] - m1r);  s1 += sc[nt][1];
                sc[nt][2] = __expf(sc[nt][2] - m2r);  s2 += sc[nt][2];
                sc[nt][3] = __expf(sc[nt][3] - m3r);  s3 += sc[nt][3];
            }
#pragma unroll
            for (int off = 1; off < 16; off <<= 1) {
                s0 += __shfl_xor(s0, off);
                s1 += __shfl_xor(s1, off);
                s2 += __shfl_xor(s2, off);
                s3 += __shfl_xor(s3, off);
            }
            s0 = 1.f / s0; s1 = 1.f / s1; s2 = 1.f / s2; s3 = 1.f / s3;
#pragma unroll
            for (int nt = 0; nt < 10; ++nt) {
                int cb = nt * 16 + l15;
                Pw[(lg * 4 + 0) * VP_ + cb] = __float2bfloat16(sc[nt][0]);
                Pw[(lg * 4 + 1) * VP_ + cb] = __float2bfloat16(sc[nt][1]);
                Pw[(lg * 4 + 2) * VP_ + cb] = __float2bfloat16(sc[nt][2]);
                Pw[(lg * 4 + 3) * VP_ + cb] = __float2bfloat16(sc[nt][3]);
            }
            f32x4 oc[4] = {};
#pragma unroll
            for (int nc = 0; nc < 5; ++nc) {
                bf16x8 pa = *(const bf16x8*)((const unsigned short*)Pw + l15 * VP_ + nc * 32 + lg * 8);
#pragma unroll
                for (int dt = 0; dt < 4; ++dt) {
                    bf16x8 vb = *(const bf16x8*)(Vt + (dt * 16 + l15) * VP_ + nc * 32 + lg * 8);
                    oc[dt] = __builtin_amdgcn_mfma_f32_16x16x32_bf16(pa, vb, oc[dt], 0, 0, 0);
                }
            }
            int orow = mt * 16 + lg * 4;
#pragma unroll
            for (int dt = 0; dt < 4; ++dt) {
                int d = h * 64 + dt * 16 + l15;
                if (orow + 0 < 151) obf[((size_t)(b * S_ + orow + 0)) * E_ + d] = __float2bfloat16(oc[dt][0] * s0);
                if (orow + 1 < 151) obf[((size_t)(b * S_ + orow + 1)) * E_ + d] = __float2bfloat16(oc[dt][1] * s1);
                if (orow + 2 < 151) obf[((size_t)(b * S_ + orow + 2)) * E_ + d] = __float2bfloat16(oc[dt][2] * s2);
                if (orow + 3 < 151) obf[((size_t)(b * S_ + orow + 3)) * E_ + d] = __float2bfloat16(oc[dt][3] * s3);
            }
        }
    }
}

// ---------------- fused residual + LayerNorm, bf16 stream (4 rows/block) -----
__global__ __launch_bounds__(256)
void ln_res_kernel(const bf16* __restrict__ t_bf, const float* __restrict__ gw,
                   const float* __restrict__ bw, bf16* __restrict__ xbf) {
    int lane = threadIdx.x & 63;
    int row = blockIdx.x * 4 + (threadIdx.x >> 6);
    size_t o = (size_t)row * E_ + lane * 8;
    u16x8 xv = *(const u16x8*)((const unsigned short*)xbf + o);
    u16x8 tv = *(const u16x8*)((const unsigned short*)t_bf + o);
    f32x4 t0, t1;
    t0[0] = b2f(xv[0]) + b2f(tv[0]); t0[1] = b2f(xv[1]) + b2f(tv[1]);
    t0[2] = b2f(xv[2]) + b2f(tv[2]); t0[3] = b2f(xv[3]) + b2f(tv[3]);
    t1[0] = b2f(xv[4]) + b2f(tv[4]); t1[1] = b2f(xv[5]) + b2f(tv[5]);
    t1[2] = b2f(xv[6]) + b2f(tv[6]); t1[3] = b2f(xv[7]) + b2f(tv[7]);
    float s = t0[0] + t0[1] + t0[2] + t0[3] + t1[0] + t1[1] + t1[2] + t1[3];
#pragma unroll
    for (int off = 1; off < 64; off <<= 1) s += __shfl_xor(s, off);
    float mean = s * (1.0f / 512.0f);
    f32x4 d0 = t0 - mean, d1 = t1 - mean;
    float q = d0[0]*d0[0] + d0[1]*d0[1] + d0[2]*d0[2] + d0[3]*d0[3]
            + d1[0]*d1[0] + d1[1]*d1[1] + d1[2]*d1[2] + d1[3]*d1[3];
#pragma unroll
    for (int off = 1; off < 64; off <<= 1) q += __shfl_xor(q, off);
    float rstd = rsqrtf(q * (1.0f / 512.0f) + 1e-5f);
    f32x4 g0 = *(const f32x4*)(gw + lane * 8);
    f32x4 g1 = *(const f32x4*)(gw + lane * 8 + 4);
    f32x4 bb0 = *(const f32x4*)(bw + lane * 8);
    f32x4 bb1 = *(const f32x4*)(bw + lane * 8 + 4);
    f32x4 y0 = d0 * rstd * g0 + bb0;
    f32x4 y1 = d1 * rstd * g1 + bb1;
    union { unsigned short s[8]; uint4 v; } pk;
    pk.s[0] = f2b(y0[0]); pk.s[1] = f2b(y0[1]); pk.s[2] = f2b(y0[2]); pk.s[3] = f2b(y0[3]);
    pk.s[4] = f2b(y1[0]); pk.s[5] = f2b(y1[1]); pk.s[6] = f2b(y1[2]); pk.s[7] = f2b(y1[3]);
    *(uint4*)((unsigned short*)xbf + o) = pk.v;
}

// ---------------- final: out[b,:] = f32(xbf[b*S + 0, :]) ---------------------
__global__ __launch_bounds__(256)
void out_kernel(const bf16* __restrict__ xbf, float* __restrict__ out) {
    int i = blockIdx.x * 256 + threadIdx.x;
    int b = i >> 9, e = i & 511;
    out[i] = b2f(((const unsigned short*)xbf)[(size_t)b * S_ * E_ + e]);
}

extern "C" void kernel_launch(void* const* d_in, const int* in_sizes, int n_in,
                              void* d_out, int out_size, void* d_ws, size_t ws_size,
                              hipStream_t stream) {
    (void)in_sizes; (void)n_in; (void)out_size; (void)ws_size;
    const int*   token_type = (const int*)d_in[0];
    const int*   mask       = (const int*)d_in[1];
    const int*   dec_idx    = (const int*)d_in[2];
    const float* action_val = (const float*)d_in[3];
    const float* dis_val    = (const float*)d_in[4];
    const float* v_val      = (const float*)d_in[5];
    const float* action_W   = (const float*)d_in[6];
    const float* action_b   = (const float*)d_in[7];
    const float* dis_W      = (const float*)d_in[8];
    const float* dis_b      = (const float*)d_in[9];
    const float* v_W        = (const float*)d_in[10];
    const float* v_b        = (const float*)d_in[11];
    const float* dec_emb    = (const float*)d_in[12];
    const float* pos        = (const float*)d_in[13];
    const float* cls        = (const float*)d_in[14];
    const float* qkv_W      = (const float*)d_in[15];
    const float* qkv_b      = (const float*)d_in[16];
    const float* out_W      = (const float*)d_in[17];
    const float* out_b      = (const float*)d_in[18];
    const float* ln1_g      = (const float*)d_in[19];
    const float* ln1_b      = (const float*)d_in[20];
    const float* ff1_W      = (const float*)d_in[21];
    const float* ff1_b      = (const float*)d_in[22];
    const float* ff2_W      = (const float*)d_in[23];
    const float* ff2_b      = (const float*)d_in[24];
    const float* ln2_g      = (const float*)d_in[25];
    const float* ln2_b      = (const float*)d_in[26];

    // allow 128KB dynamic LDS for the 256x256 pipelined GEMM
    (void)hipFuncSetAttribute(reinterpret_cast<const void*>(gemm8p_kernel<3>),
                        hipFuncAttributeMaxDynamicSharedMemorySize, 131072);
    (void)hipFuncSetAttribute(reinterpret_cast<const void*>(gemm8p_kernel<1>),
                        hipFuncAttributeMaxDynamicSharedMemorySize, 131072);

    // ---- workspace: ~236 MB; xbf BEFORE arena so A-staging over-reads of the
    // partial last m-tile (<=256 rows * 1KB) land in owned memory.
    char* ws = (char*)d_ws;
    size_t off = 0;
    auto alloc = [&](size_t bytes) {
        char* p = ws + off;
        off += (bytes + 255) & ~(size_t)255;
        return p;
    };
    bf16* qkvT = (bf16*)alloc((size_t)L_ * 1536 * 512 * 2);  //  9.4 MB
    bf16* outT = (bf16*)alloc((size_t)L_ * 512 * 512 * 2);   //  3.1 MB
    bf16* ff1T = (bf16*)alloc((size_t)L_ * 2048 * 512 * 2);  // 12.6 MB
    bf16* ff2T = (bf16*)alloc((size_t)L_ * 512 * 2048 * 2);  // 12.6 MB
    bf16*  xbf = (bf16*)alloc((size_t)M_ * E_ * 2);          // 39.6 MB bf16 residual x
    bf16* arena = (bf16*)alloc((size_t)M_ * 2048 * 2);       // 158.3 MB shared scratch
    bf16* qkvbf  = arena;                                    // M*1536 (qkv out)
    bf16* obf    = arena + (size_t)M_ * 1536;                // M*512 (attn out)
    bf16* projout= arena;                                    // M*512 (proj out)
    bf16* hbf    = arena + (size_t)M_ * 512;                 // half-M*2048 (ff1 out)
    bf16* t2     = arena + (size_t)M_ * 1536;                // half-M*512 (ff2 out)

    dim3 blk(256);
    transpose_cast_kernel<<<dim3(8, 24, L_), blk, 0, stream>>>(qkv_W, qkvT, 512, 1536);
    transpose_cast_kernel<<<dim3(8, 8,  L_), blk, 0, stream>>>(out_W, outT, 512, 512);
    transpose_cast_kernel<<<dim3(8, 32, L_), blk, 0, stream>>>(ff1_W, ff1T, 512, 2048);
    transpose_cast_kernel<<<dim3(32, 8, L_), blk, 0, stream>>>(ff2_W, ff2T, 2048, 512);

    embed_kernel<<<dim3(M_ / 4), blk, 0, stream>>>(token_type, dec_idx, action_val, dis_val, v_val,
        action_W, action_b, dis_W, dis_b, v_W, v_b, dec_emb, pos, cls, xbf);

    const int HALF_ROWS = 19328;   // 75.5 m-tiles of 256 -> 76 clamped

    for (int l = 0; l < L_; ++l) {
        const bf16* qT = qkvT + (size_t)l * 1536 * 512;
        const bf16* oT = outT + (size_t)l * 512 * 512;
        const bf16* f1 = ff1T + (size_t)l * 2048 * 512;
        const bf16* f2 = ff2T + (size_t)l * 512 * 2048;

        // QKV via 256x256 pipeline (151 m-tiles exact, 6 n-tiles -> 906 blocks)
        gemm8p_kernel<3><<<dim3(151 * 6), dim3(512), 131072, stream>>>(
            xbf, qT, qkv_b + l * 1536, qkvbf, M_, 1536, 512);
        attn_kernel<<<dim3(B_ * H_), blk, 0, stream>>>(qkvbf, mask, obf);
        // proj via 128x128 (1208 blocks); fused res+LN1 updates xbf in place
        gemm_kernel<3><<<dim3(302 * 4), blk, 0, stream>>>(
            obf, oT, out_b + l * 512, projout, 512, 512);
        ln_res_kernel<<<dim3(M_ / 4), blk, 0, stream>>>(
            projout, ln1_g + l * 512, ln1_b + l * 512, xbf);
        // FF, 2 half-chunks: ff1 via 256x256 (76x8=608 blocks), ff2 via 128x128
        for (int c = 0; c < 2; ++c) {
            size_t rb = (size_t)c * HALF_ROWS;
            gemm8p_kernel<1><<<dim3(76 * 8), dim3(512), 131072, stream>>>(
                xbf + rb * E_, f1, ff1_b + l * 2048, hbf, HALF_ROWS, 2048, 512);
            gemm_kernel<3><<<dim3(151 * 4), blk, 0, stream>>>(
                hbf, f2, ff2_b + l * 512, t2, 512, 2048);
            ln_res_kernel<<<dim3(HALF_ROWS / 4), blk, 0, stream>>>(
                t2, ln2_g + l * 512, ln2_b + l * 512, xbf + rb * E_);
        }
    }
    out_kernel<<<dim3(B_ * E_ / 256), blk, 0, stream>>>(xbf, (float*)d_out);
}

// Round 11
// 2119.307 us; speedup vs baseline: 1.7356x; 1.5150x over previous
//
#include <hip/hip_runtime.h>
#include <hip/hip_bf16.h>
#include <stdint.h>

#define B_ 256
#define T_ 150
#define S_ 151
#define E_ 512
#define H_ 8
#define L_ 6
#define FF_ 2048
#define M_ (B_*S_)   // 38656 = 302*128 = 151*256

typedef __hip_bfloat16 bf16;
typedef __bf16 bf16x8 __attribute__((ext_vector_type(8)));
typedef float f32x4 __attribute__((ext_vector_type(4)));
typedef unsigned short u16x8 __attribute__((ext_vector_type(8)));

__device__ inline unsigned short f2b(float x) {
    union { __hip_bfloat16 h; unsigned short u; } c;
    c.h = __float2bfloat16(x);
    return c.u;
}
__device__ inline float b2f(unsigned short u) {
    union { uint32_t u; float f; } c;
    c.u = (uint32_t)u << 16;
    return c.f;
}

// async global->LDS 16B; LDS dest must be wave-uniform base + lane*16 (linear)
__device__ __forceinline__ void gl16(const void* g, void* l) {
    __builtin_amdgcn_global_load_lds(
        (const __attribute__((address_space(1))) unsigned int*)g,
        (__attribute__((address_space(3))) unsigned int*)l, 16, 0, 0);
}

// ---------------- weight transpose f32[K][N] -> bf16[N][K], batched over L ----
__global__ __launch_bounds__(256)
void transpose_cast_kernel(const float* __restrict__ src, bf16* __restrict__ dst,
                           int K, int N) {
    __shared__ float tile[64][65];
    int l = blockIdx.z;
    const float* s = src + (size_t)l * K * N;
    bf16* d = dst + (size_t)l * K * N;
    int bk = blockIdx.x * 64, bn = blockIdx.y * 64;
    int col = threadIdx.x & 63, rg = threadIdx.x >> 6;
#pragma unroll
    for (int i = 0; i < 16; ++i) {
        int r = i * 4 + rg;
        tile[r][col] = s[(size_t)(bk + r) * N + bn + col];
    }
    __syncthreads();
#pragma unroll
    for (int i = 0; i < 16; ++i) {
        int r = i * 4 + rg;
        d[(size_t)(bn + r) * K + bk + col] = __float2bfloat16(tile[col][r]);
    }
}

// ---------------- token embedding + pos + cls -> xbf (4 rows/block) ----------
__global__ __launch_bounds__(256)
void embed_kernel(const int* __restrict__ tt, const int* __restrict__ dec_idx,
                  const float* __restrict__ action_val, const float* __restrict__ dis_val,
                  const float* __restrict__ v_val,
                  const float* __restrict__ action_W, const float* __restrict__ action_b,
                  const float* __restrict__ dis_W, const float* __restrict__ dis_b,
                  const float* __restrict__ v_W, const float* __restrict__ v_b,
                  const float* __restrict__ dec_emb, const float* __restrict__ pos,
                  const float* __restrict__ cls,
                  bf16* __restrict__ xbf) {
    int lane = threadIdx.x & 63;
    int bs = blockIdx.x * 4 + (threadIdx.x >> 6);
    int b = bs / S_, s = bs - b * S_;
    int e0 = lane * 8;
    f32x4 v0, v1;
    if (s == 0) {
        v0 = *(const f32x4*)(cls + e0);
        v1 = *(const f32x4*)(cls + e0 + 4);
    } else {
        int t = s - 1;
        int ty = tt[b * T_ + t];
        if (ty == 0) {
            float av = action_val[b * T_ + t];
            f32x4 w0 = *(const f32x4*)(action_W + e0);
            f32x4 w1 = *(const f32x4*)(action_W + e0 + 4);
            f32x4 b0 = *(const f32x4*)(action_b + e0);
            f32x4 b1 = *(const f32x4*)(action_b + e0 + 4);
            v0 = w0 * av + b0;  v1 = w1 * av + b1;
        } else if (ty == 1) {
            v0 = *(const f32x4*)(dis_b + e0) + *(const f32x4*)(v_b + e0);
            v1 = *(const f32x4*)(dis_b + e0 + 4) + *(const f32x4*)(v_b + e0 + 4);
#pragma unroll
            for (int i = 0; i < 10; ++i) {
                float dv = dis_val[(b * T_ + t) * 10 + i];
                v0 += *(const f32x4*)(dis_W + i * E_ + e0) * dv;
                v1 += *(const f32x4*)(dis_W + i * E_ + e0 + 4) * dv;
            }
#pragma unroll
            for (int i = 0; i < 3; ++i) {
                float vv = v_val[(b * T_ + t) * 3 + i];
                v0 += *(const f32x4*)(v_W + i * E_ + e0) * vv;
                v1 += *(const f32x4*)(v_W + i * E_ + e0 + 4) * vv;
            }
        } else {
            const float* de = dec_emb + (size_t)dec_idx[b * T_ + t] * E_;
            v0 = *(const f32x4*)(de + e0);
            v1 = *(const f32x4*)(de + e0 + 4);
        }
        v0 += *(const f32x4*)(pos + (size_t)t * E_ + e0);
        v1 += *(const f32x4*)(pos + (size_t)t * E_ + e0 + 4);
    }
    size_t o = (size_t)bs * E_ + e0;
    union { unsigned short s[8]; uint4 v; } pk;
    pk.s[0] = f2b(v0[0]); pk.s[1] = f2b(v0[1]); pk.s[2] = f2b(v0[2]); pk.s[3] = f2b(v0[3]);
    pk.s[4] = f2b(v1[0]); pk.s[5] = f2b(v1[1]); pk.s[6] = f2b(v1[2]); pk.s[7] = f2b(v1[3]);
    *(uint4*)((unsigned short*)xbf + o) = pk.v;
}

// ---------------- bf16 MFMA GEMM 128x128 (R7-proven) -------------------------
// MODE: 1 = relu(acc+bias) -> bf16 | 3 = acc+bias -> bf16
template<int MODE>
__global__ __launch_bounds__(256, 2)
void gemm_kernel(const bf16* __restrict__ A, const bf16* __restrict__ Bt,
                 const float* __restrict__ bias, bf16* __restrict__ Cb,
                 int N, int K) {
    __shared__ alignas(16) bf16 As[128][64];
    __shared__ alignas(16) bf16 Bs[128][64];
    const int tid = threadIdx.x;
    const int wave = tid >> 6, lane = tid & 63;
    const int nwg = gridDim.x, bid = blockIdx.x;
    const int Nt = N >> 7;
    const int q = nwg >> 3, r = nwg & 7;
    const int xcd = bid & 7, slot = bid >> 3;
    const int wgid = (xcd < r ? xcd * (q + 1) : r * (q + 1) + (xcd - r) * q) + slot;
    const int mt = wgid / Nt, ntl = wgid - mt * Nt;
    const int m0 = mt * 128, n0 = ntl * 128;
    const int wm = (wave >> 1) * 64, wn = (wave & 1) * 64;
    const int l15 = lane & 15, lg = lane >> 4;

    f32x4 acc[4][4] = {};

    for (int k0 = 0; k0 < K; k0 += 64) {
#pragma unroll
        for (int i = 0; i < 4; ++i) {
            int chunk = i * 256 + tid;      // 0..1023
            int row = chunk >> 3, cl = chunk & 7;
            int gc = cl ^ (row & 7);
            gl16(A + (size_t)(m0 + row) * K + k0 + gc * 8,
                 (char*)&As[0][0] + chunk * 16);
            gl16(Bt + (size_t)(n0 + row) * K + k0 + gc * 8,
                 (char*)&Bs[0][0] + chunk * 16);
        }
        __syncthreads();
#pragma unroll
        for (int kf = 0; kf < 2; ++kf) {
            bf16x8 af[4], bfr[4];
#pragma unroll
            for (int mf = 0; mf < 4; ++mf) {
                int row = wm + mf * 16 + l15;
                int csw = (kf * 4 + lg) ^ (row & 7);
                af[mf] = *(const bf16x8*)((const char*)&As[0][0] + row * 128 + csw * 16);
            }
#pragma unroll
            for (int nf = 0; nf < 4; ++nf) {
                int row = wn + nf * 16 + l15;
                int csw = (kf * 4 + lg) ^ (row & 7);
                bfr[nf] = *(const bf16x8*)((const char*)&Bs[0][0] + row * 128 + csw * 16);
            }
#pragma unroll
            for (int mf = 0; mf < 4; ++mf)
#pragma unroll
                for (int nf = 0; nf < 4; ++nf)
                    acc[mf][nf] = __builtin_amdgcn_mfma_f32_16x16x32_bf16(
                        af[mf], bfr[nf], acc[mf][nf], 0, 0, 0);
        }
        __syncthreads();
    }
#pragma unroll
    for (int nf = 0; nf < 4; ++nf) {
        int col = n0 + wn + nf * 16 + l15;
        float bv = bias[col];
#pragma unroll
        for (int mf = 0; mf < 4; ++mf) {
#pragma unroll
            for (int j = 0; j < 4; ++j) {
                int row = m0 + wm + mf * 16 + lg * 4 + j;
                size_t idx = (size_t)row * N + col;
                float x = acc[mf][nf][j] + bv;
                if (MODE == 1) x = fmaxf(x, 0.f);
                Cb[idx] = __float2bfloat16(x);
            }
        }
    }
}

// ---------------- attention: MFMA, one block per (b,h), layers 0-4 ----------
#define VP_ 168
__global__ __launch_bounds__(256, 2)
void attn_kernel(const bf16* __restrict__ qkv, const int* __restrict__ mask,
                 bf16* __restrict__ obf) {
    __shared__ alignas(16) unsigned short ldsbuf[32064];
    unsigned short* Kb = ldsbuf;                       // 10240 u16
    unsigned short* QP = ldsbuf + 10240;               // 10752 u16 (Q 10240 / Pb 10752)
    unsigned short* Vt = ldsbuf + 10240 + 10752;       // 10752 u16, [64][168]
    float* biasf = (float*)(ldsbuf + 10240 + 10752 + 10752);  // 160 f32

    const int bh = blockIdx.x;
    const int b = bh >> 3, h = bh & 7;
    const int tid = threadIdx.x, w = tid >> 6, lane = tid & 63;
    const int l15 = lane & 15, lg = lane >> 4;
    const size_t base = (size_t)b * S_ * 1536 + h * 64;
    const unsigned short* qk16 = (const unsigned short*)qkv;

    for (int i = tid; i < 160 * 8; i += 256) {
        int r = i >> 3, c = i & 7;
        int csw = c ^ (r & 7);
        uint4 kz = make_uint4(0u, 0u, 0u, 0u), qz = kz;
        if (r < 151) {
            kz = *(const uint4*)(qk16 + base + (size_t)r * 1536 + 512 + c * 8);
            qz = *(const uint4*)(qk16 + base + (size_t)r * 1536 + c * 8);
        }
        *(uint4*)((char*)Kb + r * 128 + csw * 16) = kz;
        *(uint4*)((char*)QP + r * 128 + csw * 16) = qz;
    }
    for (int i = tid; i < 160 * 8; i += 256) {
        int n = i >> 3, c = i & 7;
        u16x8 vv = {0, 0, 0, 0, 0, 0, 0, 0};
        if (n < 151) vv = *(const u16x8*)(qk16 + base + (size_t)n * 1536 + 1024 + c * 8);
#pragma unroll
        for (int e = 0; e < 8; ++e) Vt[(c * 8 + e) * VP_ + n] = vv[e];
    }
    if (tid < 160) {
        float bv;
        if (tid == 0) bv = 0.f;
        else if (tid <= 150) bv = (mask[b * T_ + tid - 1] != 0) ? 0.f : -1e9f;
        else bv = -1e9f;
        biasf[tid] = bv;
    }
    __syncthreads();

    int r0 = w * 16 + l15;
    int r1 = r0 + 64;
    int r2 = r0 + 128; if (r2 > 159) r2 = 159;
    bf16x8 q00 = *(const bf16x8*)((const char*)QP + r0 * 128 + ((lg)     ^ (r0 & 7)) * 16);
    bf16x8 q01 = *(const bf16x8*)((const char*)QP + r0 * 128 + ((4 + lg) ^ (r0 & 7)) * 16);
    bf16x8 q10 = *(const bf16x8*)((const char*)QP + r1 * 128 + ((lg)     ^ (r1 & 7)) * 16);
    bf16x8 q11 = *(const bf16x8*)((const char*)QP + r1 * 128 + ((4 + lg) ^ (r1 & 7)) * 16);
    bf16x8 q20 = *(const bf16x8*)((const char*)QP + r2 * 128 + ((lg)     ^ (r2 & 7)) * 16);
    bf16x8 q21 = *(const bf16x8*)((const char*)QP + r2 * 128 + ((4 + lg) ^ (r2 & 7)) * 16);
    float bc0 = biasf[l15],       bc1 = biasf[16 + l15],  bc2 = biasf[32 + l15];
    float bc3 = biasf[48 + l15],  bc4 = biasf[64 + l15],  bc5 = biasf[80 + l15];
    float bc6 = biasf[96 + l15],  bc7 = biasf[112 + l15], bc8 = biasf[128 + l15];
    float bc9 = biasf[144 + l15];
    __syncthreads();   // QP now becomes the per-wave P buffer

    bf16* Pw = (bf16*)(QP + w * 16 * VP_);
    const float scale = 0.125f;

#pragma unroll
    for (int mi = 0; mi < 3; ++mi) {
        int mt = w + mi * 4;
        if (mt < 10) {
            bf16x8 qk0 = (mi == 0) ? q00 : (mi == 1) ? q10 : q20;
            bf16x8 qk1 = (mi == 0) ? q01 : (mi == 1) ? q11 : q21;
            f32x4 sc[10] = {};
#pragma unroll
            for (int nt = 0; nt < 10; ++nt) {
                int kr = nt * 16 + l15;
                bf16x8 kb0 = *(const bf16x8*)((const char*)Kb + kr * 128 + ((lg)     ^ (kr & 7)) * 16);
                bf16x8 kb1 = *(const bf16x8*)((const char*)Kb + kr * 128 + ((4 + lg) ^ (kr & 7)) * 16);
                sc[nt] = __builtin_amdgcn_mfma_f32_16x16x32_bf16(qk0, kb0, sc[nt], 0, 0, 0);
                sc[nt] = __builtin_amdgcn_mfma_f32_16x16x32_bf16(qk1, kb1, sc[nt], 0, 0, 0);
            }
            float m0r = -3e38f, m1r = -3e38f, m2r = -3e38f, m3r = -3e38f;
#pragma unroll
            for (int nt = 0; nt < 10; ++nt) {
                float bv = (nt == 0) ? bc0 : (nt == 1) ? bc1 : (nt == 2) ? bc2 :
                           (nt == 3) ? bc3 : (nt == 4) ? bc4 : (nt == 5) ? bc5 :
                           (nt == 6) ? bc6 : (nt == 7) ? bc7 : (nt == 8) ? bc8 : bc9;
                sc[nt][0] = sc[nt][0] * scale + bv;  m0r = fmaxf(m0r, sc[nt][0]);
                sc[nt][1] = sc[nt][1] * scale + bv;  m1r = fmaxf(m1r, sc[nt][1]);
                sc[nt][2] = sc[nt][2] * scale + bv;  m2r = fmaxf(m2r, sc[nt][2]);
                sc[nt][3] = sc[nt][3] * scale + bv;  m3r = fmaxf(m3r, sc[nt][3]);
            }
#pragma unroll
            for (int off = 1; off < 16; off <<= 1) {
                m0r = fmaxf(m0r, __shfl_xor(m0r, off));
                m1r = fmaxf(m1r, __shfl_xor(m1r, off));
                m2r = fmaxf(m2r, __shfl_xor(m2r, off));
                m3r = fmaxf(m3r, __shfl_xor(m3r, off));
            }
            float s0 = 0.f, s1 = 0.f, s2 = 0.f, s3 = 0.f;
#pragma unroll
            for (int nt = 0; nt < 10; ++nt) {
                sc[nt][0] = __expf(sc[nt][0] - m0r);  s0 += sc[nt][0];
                sc[nt][1] = __expf(sc[nt][1] - m1r);  s1 += sc[nt][1];
                sc[nt][2] = __expf(sc[nt][2] - m2r);  s2 += sc[nt][2];
                sc[nt][3] = __expf(sc[nt][3] - m3r);  s3 += sc[nt][3];
            }
#pragma unroll
            for (int off = 1; off < 16; off <<= 1) {
                s0 += __shfl_xor(s0, off);
                s1 += __shfl_xor(s1, off);
                s2 += __shfl_xor(s2, off);
                s3 += __shfl_xor(s3, off);
            }
            s0 = 1.f / s0; s1 = 1.f / s1; s2 = 1.f / s2; s3 = 1.f / s3;
#pragma unroll
            for (int nt = 0; nt < 10; ++nt) {
                int cb = nt * 16 + l15;
                Pw[(lg * 4 + 0) * VP_ + cb] = __float2bfloat16(sc[nt][0]);
                Pw[(lg * 4 + 1) * VP_ + cb] = __float2bfloat16(sc[nt][1]);
                Pw[(lg * 4 + 2) * VP_ + cb] = __float2bfloat16(sc[nt][2]);
                Pw[(lg * 4 + 3) * VP_ + cb] = __float2bfloat16(sc[nt][3]);
            }
            f32x4 oc[4] = {};
#pragma unroll
            for (int nc = 0; nc < 5; ++nc) {
                bf16x8 pa = *(const bf16x8*)((const unsigned short*)Pw + l15 * VP_ + nc * 32 + lg * 8);
#pragma unroll
                for (int dt = 0; dt < 4; ++dt) {
                    bf16x8 vb = *(const bf16x8*)(Vt + (dt * 16 + l15) * VP_ + nc * 32 + lg * 8);
                    oc[dt] = __builtin_amdgcn_mfma_f32_16x16x32_bf16(pa, vb, oc[dt], 0, 0, 0);
                }
            }
            int orow = mt * 16 + lg * 4;
#pragma unroll
            for (int dt = 0; dt < 4; ++dt) {
                int d = h * 64 + dt * 16 + l15;
                if (orow + 0 < 151) obf[((size_t)(b * S_ + orow + 0)) * E_ + d] = __float2bfloat16(oc[dt][0] * s0);
                if (orow + 1 < 151) obf[((size_t)(b * S_ + orow + 1)) * E_ + d] = __float2bfloat16(oc[dt][1] * s1);
                if (orow + 2 < 151) obf[((size_t)(b * S_ + orow + 2)) * E_ + d] = __float2bfloat16(oc[dt][2] * s2);
                if (orow + 3 < 151) obf[((size_t)(b * S_ + orow + 3)) * E_ + d] = __float2bfloat16(oc[dt][3] * s3);
            }
        }
    }
}

// ---------------- gather cls rows: xcls[b,:] = xbf[b*S,:] --------------------
__global__ __launch_bounds__(64)
void gather_cls_kernel(const bf16* __restrict__ xbf, bf16* __restrict__ xcls) {
    int b = blockIdx.x, t = threadIdx.x;
    *(uint4*)((unsigned short*)xcls + (size_t)b * E_ + t * 8) =
        *(const uint4*)((const unsigned short*)xbf + (size_t)b * S_ * E_ + t * 8);
}

// ---------------- cls-only attention (last layer): 1 query row per (b,h) ----
// qcls [B,512]; qkvkv [M,1024] (K at 0..511, V at 512..1023, head offset h*64).
__global__ __launch_bounds__(256)
void cls_attn_kernel(const bf16* __restrict__ qcls, const bf16* __restrict__ qkvkv,
                     const int* __restrict__ mask, bf16* __restrict__ ocls) {
    __shared__ float q0[64];
    __shared__ float pb[152];
    __shared__ float red[8];
    __shared__ float opart[4][64];
    const int bh = blockIdx.x, b = bh >> 3, h = bh & 7;
    const int tid = threadIdx.x, w = tid >> 6, lane = tid & 63;
    const unsigned short* qk = (const unsigned short*)qkvkv;

    if (tid < 64) q0[tid] = b2f(((const unsigned short*)qcls)[(size_t)b * E_ + h * 64 + tid]);
    __syncthreads();

    float s = -1e30f;
    if (tid < 151) {
        const unsigned short* kr = qk + ((size_t)(b * S_ + tid)) * 1024 + h * 64;
        float acc = 0.f;
#pragma unroll
        for (int c = 0; c < 8; ++c) {
            u16x8 kv = *(const u16x8*)(kr + c * 8);
#pragma unroll
            for (int e = 0; e < 8; ++e) acc += q0[c * 8 + e] * b2f(kv[e]);
        }
        float bv = (tid == 0) ? 0.f : ((mask[b * T_ + tid - 1] != 0) ? 0.f : -1e9f);
        s = acc * 0.125f + bv;
    }
    float m = s;
#pragma unroll
    for (int off = 1; off < 64; off <<= 1) m = fmaxf(m, __shfl_xor(m, off));
    if (lane == 0) red[w] = m;
    __syncthreads();
    m = fmaxf(fmaxf(red[0], red[1]), fmaxf(red[2], red[3]));
    float p = (tid < 151) ? __expf(s - m) : 0.f;
    if (tid < 152) pb[tid] = p;
    float ss = p;
#pragma unroll
    for (int off = 1; off < 64; off <<= 1) ss += __shfl_xor(ss, off);
    if (lane == 0) red[4 + w] = ss;
    __syncthreads();
    float inv = 1.f / (red[4] + red[5] + red[6] + red[7]);
    // PV: wave w handles its j-quarter, lane = d
    int j0 = w * 38, j1 = j0 + 38; if (j1 > 151) j1 = 151;
    float o = 0.f;
    for (int j = j0; j < j1; ++j)
        o += pb[j] * b2f(qk[((size_t)(b * S_ + j)) * 1024 + 512 + h * 64 + lane]);
    opart[w][lane] = o;
    __syncthreads();
    if (tid < 64) {
        float oo = (opart[0][tid] + opart[1][tid] + opart[2][tid] + opart[3][tid]) * inv;
        ((unsigned short*)ocls)[(size_t)b * E_ + h * 64 + tid] = f2b(oo);
    }
}

// ---------------- fused residual + LayerNorm, bf16 stream (4 rows/block) -----
__global__ __launch_bounds__(256)
void ln_res_kernel(const bf16* __restrict__ t_bf, const float* __restrict__ gw,
                   const float* __restrict__ bw, bf16* __restrict__ xbf) {
    int lane = threadIdx.x & 63;
    int row = blockIdx.x * 4 + (threadIdx.x >> 6);
    size_t o = (size_t)row * E_ + lane * 8;
    u16x8 xv = *(const u16x8*)((const unsigned short*)xbf + o);
    u16x8 tv = *(const u16x8*)((const unsigned short*)t_bf + o);
    f32x4 t0, t1;
    t0[0] = b2f(xv[0]) + b2f(tv[0]); t0[1] = b2f(xv[1]) + b2f(tv[1]);
    t0[2] = b2f(xv[2]) + b2f(tv[2]); t0[3] = b2f(xv[3]) + b2f(tv[3]);
    t1[0] = b2f(xv[4]) + b2f(tv[4]); t1[1] = b2f(xv[5]) + b2f(tv[5]);
    t1[2] = b2f(xv[6]) + b2f(tv[6]); t1[3] = b2f(xv[7]) + b2f(tv[7]);
    float s = t0[0] + t0[1] + t0[2] + t0[3] + t1[0] + t1[1] + t1[2] + t1[3];
#pragma unroll
    for (int off = 1; off < 64; off <<= 1) s += __shfl_xor(s, off);
    float mean = s * (1.0f / 512.0f);
    f32x4 d0 = t0 - mean, d1 = t1 - mean;
    float q = d0[0]*d0[0] + d0[1]*d0[1] + d0[2]*d0[2] + d0[3]*d0[3]
            + d1[0]*d1[0] + d1[1]*d1[1] + d1[2]*d1[2] + d1[3]*d1[3];
#pragma unroll
    for (int off = 1; off < 64; off <<= 1) q += __shfl_xor(q, off);
    float rstd = rsqrtf(q * (1.0f / 512.0f) + 1e-5f);
    f32x4 g0 = *(const f32x4*)(gw + lane * 8);
    f32x4 g1 = *(const f32x4*)(gw + lane * 8 + 4);
    f32x4 bb0 = *(const f32x4*)(bw + lane * 8);
    f32x4 bb1 = *(const f32x4*)(bw + lane * 8 + 4);
    f32x4 y0 = d0 * rstd * g0 + bb0;
    f32x4 y1 = d1 * rstd * g1 + bb1;
    union { unsigned short s[8]; uint4 v; } pk;
    pk.s[0] = f2b(y0[0]); pk.s[1] = f2b(y0[1]); pk.s[2] = f2b(y0[2]); pk.s[3] = f2b(y0[3]);
    pk.s[4] = f2b(y1[0]); pk.s[5] = f2b(y1[1]); pk.s[6] = f2b(y1[2]); pk.s[7] = f2b(y1[3]);
    *(uint4*)((unsigned short*)xbf + o) = pk.v;
}

// ---------------- final: out = f32(xcls) -------------------------------------
__global__ __launch_bounds__(256)
void out_cls_kernel(const bf16* __restrict__ xcls, float* __restrict__ out) {
    int i = blockIdx.x * 256 + threadIdx.x;
    out[i] = b2f(((const unsigned short*)xcls)[i]);
}

extern "C" void kernel_launch(void* const* d_in, const int* in_sizes, int n_in,
                              void* d_out, int out_size, void* d_ws, size_t ws_size,
                              hipStream_t stream) {
    (void)in_sizes; (void)n_in; (void)out_size; (void)ws_size;
    const int*   token_type = (const int*)d_in[0];
    const int*   mask       = (const int*)d_in[1];
    const int*   dec_idx    = (const int*)d_in[2];
    const float* action_val = (const float*)d_in[3];
    const float* dis_val    = (const float*)d_in[4];
    const float* v_val      = (const float*)d_in[5];
    const float* action_W   = (const float*)d_in[6];
    const float* action_b   = (const float*)d_in[7];
    const float* dis_W      = (const float*)d_in[8];
    const float* dis_b      = (const float*)d_in[9];
    const float* v_W        = (const float*)d_in[10];
    const float* v_b        = (const float*)d_in[11];
    const float* dec_emb    = (const float*)d_in[12];
    const float* pos        = (const float*)d_in[13];
    const float* cls        = (const float*)d_in[14];
    const float* qkv_W      = (const float*)d_in[15];
    const float* qkv_b      = (const float*)d_in[16];
    const float* out_W      = (const float*)d_in[17];
    const float* out_b      = (const float*)d_in[18];
    const float* ln1_g      = (const float*)d_in[19];
    const float* ln1_b      = (const float*)d_in[20];
    const float* ff1_W      = (const float*)d_in[21];
    const float* ff1_b      = (const float*)d_in[22];
    const float* ff2_W      = (const float*)d_in[23];
    const float* ff2_b      = (const float*)d_in[24];
    const float* ln2_g      = (const float*)d_in[25];
    const float* ln2_b      = (const float*)d_in[26];

    // ---- workspace: ~236 MB; xbf BEFORE arena so A-staging over-reads land
    // in owned memory.
    char* ws = (char*)d_ws;
    size_t off = 0;
    auto alloc = [&](size_t bytes) {
        char* p = ws + off;
        off += (bytes + 255) & ~(size_t)255;
        return p;
    };
    bf16* qkvT = (bf16*)alloc((size_t)L_ * 1536 * 512 * 2);  //  9.4 MB
    bf16* outT = (bf16*)alloc((size_t)L_ * 512 * 512 * 2);   //  3.1 MB
    bf16* ff1T = (bf16*)alloc((size_t)L_ * 2048 * 512 * 2);  // 12.6 MB
    bf16* ff2T = (bf16*)alloc((size_t)L_ * 512 * 2048 * 2);  // 12.6 MB
    bf16*  xbf = (bf16*)alloc((size_t)M_ * E_ * 2);          // 39.6 MB bf16 residual x
    bf16* arena = (bf16*)alloc((size_t)M_ * 2048 * 2);       // 158.3 MB shared scratch
    // layers 0-4 roles:
    bf16* qkvbf  = arena;                                    // M*1536 (qkv out)
    bf16* obf    = arena + (size_t)M_ * 1536;                // M*512 (attn out)
    bf16* projout= arena;                                    // M*512 (proj out)
    bf16* hbf    = arena + (size_t)M_ * 512;                 // half-M*2048 (ff1 out)
    bf16* t2     = arena + (size_t)M_ * 1536;                // M*512 (ff2 out, full)
    // layer-5 compact roles:
    bf16* qkvkv = arena;                                     // M*1024 (K,V only)
    bf16* xcls  = arena + (size_t)M_ * 1024;                 // 256*512
    bf16* qcls  = xcls + 131072;
    bf16* ocls  = qcls + 131072;
    bf16* projc = ocls + 131072;
    bf16* ffh   = projc + 131072;                            // 256*2048
    bf16* t2c   = ffh + 524288;

    dim3 blk(256);
    transpose_cast_kernel<<<dim3(8, 24, L_), blk, 0, stream>>>(qkv_W, qkvT, 512, 1536);
    transpose_cast_kernel<<<dim3(8, 8,  L_), blk, 0, stream>>>(out_W, outT, 512, 512);
    transpose_cast_kernel<<<dim3(8, 32, L_), blk, 0, stream>>>(ff1_W, ff1T, 512, 2048);
    transpose_cast_kernel<<<dim3(32, 8, L_), blk, 0, stream>>>(ff2_W, ff2T, 2048, 512);

    embed_kernel<<<dim3(M_ / 4), blk, 0, stream>>>(token_type, dec_idx, action_val, dis_val, v_val,
        action_W, action_b, dis_W, dis_b, v_W, v_b, dec_emb, pos, cls, xbf);

    const int HALF_ROWS = 19328;   // 151 m-tiles of 128, exact

    for (int l = 0; l < 5; ++l) {
        const bf16* qT = qkvT + (size_t)l * 1536 * 512;
        const bf16* oT = outT + (size_t)l * 512 * 512;
        const bf16* f1 = ff1T + (size_t)l * 2048 * 512;
        const bf16* f2 = ff2T + (size_t)l * 512 * 2048;

        // QKV (full M) -> qkvbf; attention (full) -> obf
        gemm_kernel<3><<<dim3(302 * 12), blk, 0, stream>>>(
            xbf, qT, qkv_b + l * 1536, qkvbf, 1536, 512);
        attn_kernel<<<dim3(B_ * H_), blk, 0, stream>>>(qkvbf, mask, obf);
        // proj (full M) -> projout; fused res+LN1 updates xbf in place
        gemm_kernel<3><<<dim3(302 * 4), blk, 0, stream>>>(
            obf, oT, out_b + l * 512, projout, 512, 512);
        ln_res_kernel<<<dim3(M_ / 4), blk, 0, stream>>>(
            projout, ln1_g + l * 512, ln1_b + l * 512, xbf);
        // FF, 2 half-chunks: ff1 -> hbf, ff2 -> t2 (full-M buffer, disjoint
        // halves), single full-M res+LN2 after both chunks
        for (int c = 0; c < 2; ++c) {
            size_t rb = (size_t)c * HALF_ROWS;
            gemm_kernel<1><<<dim3(151 * 16), blk, 0, stream>>>(
                xbf + rb * E_, f1, ff1_b + l * 2048, hbf, 2048, 512);
            gemm_kernel<3><<<dim3(151 * 4), blk, 0, stream>>>(
                hbf, f2, ff2_b + l * 512, t2 + rb * E_, 512, 2048);
        }
        ln_res_kernel<<<dim3(M_ / 4), blk, 0, stream>>>(
            t2, ln2_g + l * 512, ln2_b + l * 512, xbf);
    }

    // ---- layer 5: cls-only tail -------------------------------------------
    {
        const int l = 5;
        const bf16* qT = qkvT + (size_t)l * 1536 * 512;
        const bf16* oT = outT + (size_t)l * 512 * 512;
        const bf16* f1 = ff1T + (size_t)l * 2048 * 512;
        const bf16* f2 = ff2T + (size_t)l * 512 * 2048;

        // K,V for all rows (N=1024: qkvT rows 512..1535)
        gemm_kernel<3><<<dim3(302 * 8), blk, 0, stream>>>(
            xbf, qT + (size_t)512 * 512, qkv_b + l * 1536 + 512, qkvkv, 1024, 512);
        // gather cls rows; Q for cls rows only
        gather_cls_kernel<<<dim3(B_), dim3(64), 0, stream>>>(xbf, xcls);
        gemm_kernel<3><<<dim3(2 * 4), blk, 0, stream>>>(
            xcls, qT, qkv_b + l * 1536, qcls, 512, 512);
        // cls attention
        cls_attn_kernel<<<dim3(B_ * H_), blk, 0, stream>>>(qcls, qkvkv, mask, ocls);
        // compact tail: proj, LN1, FF, LN2 on 256 rows
        gemm_kernel<3><<<dim3(2 * 4), blk, 0, stream>>>(
            ocls, oT, out_b + l * 512, projc, 512, 512);
        ln_res_kernel<<<dim3(B_ / 4), blk, 0, stream>>>(
            projc, ln1_g + l * 512, ln1_b + l * 512, xcls);
        gemm_kernel<1><<<dim3(2 * 16), blk, 0, stream>>>(
            xcls, f1, ff1_b + l * 2048, ffh, 2048, 512);
        gemm_kernel<3><<<dim3(2 * 4), blk, 0, stream>>>(
            ffh, f2, ff2_b + l * 512, t2c, 512, 2048);
        ln_res_kernel<<<dim3(B_ / 4), blk, 0, stream>>>(
            t2c, ln2_g + l * 512, ln2_b + l * 512, xcls);
    }
    out_cls_kernel<<<dim3(B_ * E_ / 256), blk, 0, stream>>>(xcls, (float*)d_out);
}